// Round 20
// baseline (354.647 us; speedup 1.0000x reference)
//
#include <hip/hip_runtime.h>
#include <hip/hip_bf16.h>
#include <math.h>

#define T_TOK 2048
#define H_DIM 768
#define E_NUM 8
#define K_TOP 2
#define DF_DIM 3072
#define L_NUM 2
#define LN_EPS 1e-5f
#define NPAIR (T_TOK * K_TOP)

typedef __hip_bfloat16 bf16;
typedef __attribute__((ext_vector_type(8))) short bf16x8;   // 8 bf16 = 4 VGPRs
typedef __attribute__((ext_vector_type(4))) float f32x4;

// ---------------- f32->bf16 conversion (grid-strided, split by matrix) ----------------
__global__ __launch_bounds__(256) void conv_all(const float* __restrict__ s1,
                                                const float* __restrict__ s2,
                                                bf16* __restrict__ d1,
                                                bf16* __restrict__ d2, int n8) {
    int half = gridDim.x >> 1;
    const float* src = (blockIdx.x < half) ? s1 : s2;
    bf16* dst        = (blockIdx.x < half) ? d1 : d2;
    int bid = (blockIdx.x < half) ? blockIdx.x : blockIdx.x - half;
    int stride = half * blockDim.x;
    for (int i = bid * blockDim.x + threadIdx.x; i < n8; i += stride) {
        float4 a = ((const float4*)src)[i * 2];
        float4 b = ((const float4*)src)[i * 2 + 1];
        union { bf16 h[8]; uint4 u; } p;
        p.h[0] = __float2bfloat16(a.x); p.h[1] = __float2bfloat16(a.y);
        p.h[2] = __float2bfloat16(a.z); p.h[3] = __float2bfloat16(a.w);
        p.h[4] = __float2bfloat16(b.x); p.h[5] = __float2bfloat16(b.y);
        p.h[6] = __float2bfloat16(b.z); p.h[7] = __float2bfloat16(b.w);
        ((uint4*)dst)[i] = p.u;
    }
}

// ---------------- LN + gate logits, with fused input production ----------------
template<int FUSE>
__global__ __launch_bounds__(256) void ln_gate(
    const int* __restrict__ ids, const float* __restrict__ embed,
    const float* __restrict__ op, const int* __restrict__ inv,
    const int* __restrict__ topi, const float* __restrict__ topw,
    const float* __restrict__ b2,
    float* __restrict__ x, const float* __restrict__ g, const float* __restrict__ b,
    const float* __restrict__ gw, const float* __restrict__ gb,
    bf16* __restrict__ flat, float* __restrict__ logits_tok)
{
    int t = blockIdx.x;
    int tid = threadIdx.x;
    __shared__ float s[H_DIM];
    __shared__ float red[8];

    float v0, v1, v2;
    if (FUSE == 0) {
        const float* src = embed + (size_t)ids[t] * H_DIM;
        v0 = src[tid]; v1 = src[tid + 256]; v2 = src[tid + 512];
    } else {
        const float* xr = x + (size_t)t * H_DIM;
        int p0 = inv[t * 2], p1 = inv[t * 2 + 1];
        int e0 = topi[t * 2], e1 = topi[t * 2 + 1];
        float w0 = topw[t * 2], w1 = topw[t * 2 + 1];
        const float* o00 = op + (size_t)p0 * H_DIM;
        const float* o01 = op + ((size_t)NPAIR + p0) * H_DIM;
        const float* o10 = op + (size_t)p1 * H_DIM;
        const float* o11 = op + ((size_t)NPAIR + p1) * H_DIM;
        const float* bb0 = b2 + (size_t)e0 * H_DIM;
        const float* bb1 = b2 + (size_t)e1 * H_DIM;
        #pragma unroll
        for (int q = 0; q < 3; q++) {
            int o = tid + q * 256;
            float a0 = o00[o] + o01[o] + bb0[o];
            float a1 = o10[o] + o11[o] + bb1[o];
            float vv = xr[o] + w0 * a0 + w1 * a1;
            if (q == 0) v0 = vv; else if (q == 1) v1 = vv; else v2 = vv;
        }
    }
    float* xw = x + (size_t)t * H_DIM;
    xw[tid] = v0; xw[tid + 256] = v1; xw[tid + 512] = v2;

    float sum = v0 + v1 + v2;
    #pragma unroll
    for (int o = 32; o > 0; o >>= 1) sum += __shfl_down(sum, o);
    int wave = tid >> 6, lane = tid & 63;
    if (lane == 0) red[wave] = sum;
    __syncthreads();
    if (tid == 0) red[4] = (red[0] + red[1] + red[2] + red[3]) * (1.0f / H_DIM);
    __syncthreads();
    float mean = red[4];

    float d0 = v0 - mean, d1 = v1 - mean, d2 = v2 - mean;
    float ss = d0 * d0 + d1 * d1 + d2 * d2;
    #pragma unroll
    for (int o = 32; o > 0; o >>= 1) ss += __shfl_down(ss, o);
    if (lane == 0) red[wave] = ss;
    __syncthreads();
    if (tid == 0) red[4] = rsqrtf((red[0] + red[1] + red[2] + red[3]) * (1.0f / H_DIM) + LN_EPS);
    __syncthreads();
    float inv_s = red[4];

    float n0 = d0 * inv_s * g[tid]       + b[tid];
    float n1 = d1 * inv_s * g[tid + 256] + b[tid + 256];
    float n2 = d2 * inv_s * g[tid + 512] + b[tid + 512];
    s[tid] = n0; s[tid + 256] = n1; s[tid + 512] = n2;
    bf16* fr = flat + (size_t)t * H_DIM;
    fr[tid] = __float2bfloat16(n0);
    fr[tid + 256] = __float2bfloat16(n1);
    fr[tid + 512] = __float2bfloat16(n2);
    __syncthreads();

    #pragma unroll
    for (int ei = 0; ei < 2; ++ei) {
        int e = wave * 2 + ei;
        float p = 0.0f;
        const float* wrow = gw + (size_t)e * H_DIM;
        for (int j = lane; j < H_DIM; j += 64) p += s[j] * wrow[j];
        #pragma unroll
        for (int o = 32; o > 0; o >>= 1) p += __shfl_down(p, o);
        if (lane == 0) logits_tok[(size_t)t * E_NUM + e] = p + gb[e];
    }
}

// ---------------- routing: top2 + softmax + reduce + offsets + compaction ----------------
__global__ __launch_bounds__(1024) void route(
    const float* __restrict__ logits_tok,
    int* __restrict__ topi, float* __restrict__ topw,
    int* __restrict__ cnt, int* __restrict__ offs,
    int* __restrict__ pair_tok, int* __restrict__ inv,
    float* __restrict__ laux, float* __restrict__ counts_out)
{
    int tid = threadIdx.x;
    float pprob[E_NUM] = {0,0,0,0,0,0,0,0};
    int pcnt[E_NUM] = {0,0,0,0,0,0,0,0};
    int te[2][2];

    #pragma unroll
    for (int it = 0; it < 2; it++) {
        int t = tid + it * 1024;
        const float4* lp = (const float4*)(logits_tok + (size_t)t * E_NUM);
        float4 l0 = lp[0], l1 = lp[1];
        float lg[E_NUM] = {l0.x, l0.y, l0.z, l0.w, l1.x, l1.y, l1.z, l1.w};
        int i0 = 0; float m0 = lg[0];
        #pragma unroll
        for (int e = 1; e < E_NUM; e++) if (lg[e] > m0) { m0 = lg[e]; i0 = e; }
        int i1 = -1; float m1 = -1e30f;
        #pragma unroll
        for (int e = 0; e < E_NUM; e++) if (e != i0 && lg[e] > m1) { m1 = lg[e]; i1 = e; }
        float e1 = expf(m1 - m0);
        float is = 1.0f / (1.0f + e1);
        topi[t * 2] = i0; topi[t * 2 + 1] = i1;
        topw[t * 2] = is; topw[t * 2 + 1] = e1 * is;
        te[it][0] = i0; te[it][1] = i1;
        pcnt[i0]++; pcnt[i1]++;
        float sm = 0.0f, pe[E_NUM];
        #pragma unroll
        for (int e = 0; e < E_NUM; e++) { pe[e] = expf(lg[e] - m0); sm += pe[e]; }
        float isv = 1.0f / sm;
        #pragma unroll
        for (int e = 0; e < E_NUM; e++) pprob[e] += pe[e] * isv;
    }

    #pragma unroll
    for (int o = 32; o > 0; o >>= 1) {
        #pragma unroll
        for (int e = 0; e < E_NUM; e++) {
            pprob[e] += __shfl_down(pprob[e], o);
            pcnt[e]  += __shfl_down(pcnt[e], o);
        }
    }
    __shared__ float wprob[16][E_NUM];
    __shared__ int   wcnt[16][E_NUM];
    __shared__ int   soffs[E_NUM];
    __shared__ int   lfill[E_NUM];
    int wv = tid >> 6, lane = tid & 63;
    if (lane == 0) {
        #pragma unroll
        for (int e = 0; e < E_NUM; e++) { wprob[wv][e] = pprob[e]; wcnt[wv][e] = pcnt[e]; }
    }
    if (tid < E_NUM) lfill[tid] = 0;
    __syncthreads();
    if (tid == 0) {
        float ps[E_NUM]; int cs[E_NUM];
        #pragma unroll
        for (int e = 0; e < E_NUM; e++) {
            float p = 0.0f; int c = 0;
            for (int w = 0; w < 16; w++) { p += wprob[w][e]; c += wcnt[w][e]; }
            ps[e] = p; cs[e] = c;
        }
        int run = 0;
        #pragma unroll
        for (int e = 0; e < E_NUM; e++) { offs[e] = run; soffs[e] = run; cnt[e] = cs[e]; run += cs[e]; }
        float la = 0.0f;
        #pragma unroll
        for (int e = 0; e < E_NUM; e++) { float p = ps[e] * (1.0f / T_TOK); la += p * p; }
        laux[0] += la * E_NUM;
        #pragma unroll
        for (int e = 0; e < E_NUM; e++) counts_out[e] += (float)cs[e];
    }
    __syncthreads();

    #pragma unroll
    for (int it = 0; it < 2; it++) {
        int t = tid + it * 1024;
        #pragma unroll
        for (int k = 0; k < K_TOP; k++) {
            int e = te[it][k];
            int pos = atomicAdd(&lfill[e], 1);
            int p = soffs[e] + pos;
            pair_tok[p] = t;
            inv[t * 2 + k] = p;
        }
    }
}

// ---------------- MFMA grouped GEMM (gload_lds, BK=64, single-buffer, 2-barrier) ----
// grid: (X, E, 32) m-slot slowest. KS=1: x=n; KS=2: x=(n<<1)|ks.
// LDS rows are 128 B (64 bf16); chunk-XOR swizzle cc = c ^ (row&7), c in 0..7.
// gload_lds width=16: linear dest; per-lane inverse-swizzled global source:
//   rl = lane>>3 (8 rows/issue), c2 = (lane&7) ^ rl, global col = c2*8.
// Per K64-step: one staging volley + 2 barriers + 2x(4xNF) MFMAs (two k-substeps).
// MODE 0 (fc1): out = h1 bf16 with bias+GELU. MODE 1 (fc2): out = op[ks] f32 partial.
template<int NF, int MODE, int KDIM, int NTOT, int KS>
__global__ __launch_bounds__(256) void moe_gemm(
    const bf16* __restrict__ Abase, const bf16* __restrict__ Wbase,
    const float* __restrict__ bias,
    const int* __restrict__ cnt, const int* __restrict__ offs,
    const int* __restrict__ pair_tok, void* __restrict__ outp)
{
    constexpr int BM = 128;
    constexpr int BN = 32 * NF;
    constexpr int NISS = (BM + BN) / 8;    // 1KB issues per K64-step (8 rows each)
    constexpr int IPW  = NISS / 4;         // issues per wave
    constexpr int KD   = KDIM / KS;        // K range per block

    int e = blockIdx.y;
    int c = cnt[e];
    int m0 = blockIdx.z * BM;
    if (m0 >= c) return;
    int n0, ks;
    if (KS == 1) { n0 = blockIdx.x * BN; ks = 0; }
    else         { n0 = (blockIdx.x >> 1) * BN; ks = blockIdx.x & 1; }
    int kfirst = ks * KD;
    int seg = offs[e];
    const bf16* W = Wbase + (size_t)e * NTOT * KDIM;

    __shared__ char smem[(BM + BN) * 128]; // 128B rows, swizzled layout

    int tid = threadIdx.x;
    int lane = tid & 63, wv = tid >> 6;

    // ---- inverse-swizzle lane mapping ----
    int rl  = lane >> 3;                   // row within 8-row issue
    int c2  = (lane & 7) ^ rl;             // chunk 0..7 (8 bf16 each)

    // ---- per-issue global src (per-lane) + linear LDS dest (wave-uniform) ----
    const bf16* gsrc[IPW];
    char* ldst[IPW];
    #pragma unroll
    for (int q = 0; q < IPW; q++) {
        int j = wv + q * 4;                // issue id 0..NISS-1
        if (j < BM / 8) {                  // A rows (16 issues)
            int row = j * 8 + rl;
            int m = m0 + row;
            int mm = (m < c) ? m : (c - 1);
            if (MODE == 0)
                gsrc[q] = Abase + (size_t)pair_tok[seg + mm] * KDIM + c2 * 8;
            else
                gsrc[q] = Abase + (size_t)(seg + mm) * KDIM + c2 * 8;
            ldst[q] = smem + j * 1024;
        } else {                           // B rows
            int row = (j - BM / 8) * 8 + rl;
            gsrc[q] = W + (size_t)(n0 + row) * KDIM + c2 * 8;
            ldst[q] = smem + BM * 128 + (j - BM / 8) * 1024;
        }
    }

    // ---- fragment read offsets: [mf/nf][sub], chunk = (kbf | sub<<2) ^ (row&7) ----
    int wm = wv >> 1, wn = wv & 1;
    int kbf = lane >> 4;                   // 0..3
    int aoff[4][2], boff[NF][2];
    #pragma unroll
    for (int mf = 0; mf < 4; mf++) {
        int row = wm * 64 + mf * 16 + (lane & 15);
        #pragma unroll
        for (int sub = 0; sub < 2; sub++)
            aoff[mf][sub] = row * 128 + (((kbf | (sub << 2)) ^ (row & 7)) << 4);
    }
    #pragma unroll
    for (int nf = 0; nf < NF; nf++) {
        int row = wn * NF * 16 + nf * 16 + (lane & 15);
        #pragma unroll
        for (int sub = 0; sub < 2; sub++)
            boff[nf][sub] = BM * 128 + row * 128 + (((kbf | (sub << 2)) ^ (row & 7)) << 4);
    }

    f32x4 acc[4][NF];
    #pragma unroll
    for (int i = 0; i < 4; i++)
        #pragma unroll
        for (int j = 0; j < NF; j++) acc[i][j] = (f32x4){0.f, 0.f, 0.f, 0.f};

    // ---- K loop (BK=64: 1 staging volley + 2 barriers + 2 MFMA substeps) ----
    for (int k0 = kfirst; k0 < kfirst + KD; k0 += 64) {
        #pragma unroll
        for (int q = 0; q < IPW; q++) {
            __builtin_amdgcn_global_load_lds(
                (const __attribute__((address_space(1))) void*)(gsrc[q] + k0),
                (__attribute__((address_space(3))) void*)ldst[q],
                16, 0, 0);
        }
        __syncthreads();
        #pragma unroll
        for (int sub = 0; sub < 2; sub++) {
            bf16x8 af[4], bfr[NF];
            #pragma unroll
            for (int mf = 0; mf < 4; mf++) af[mf] = *(const bf16x8*)(smem + aoff[mf][sub]);
            #pragma unroll
            for (int nf = 0; nf < NF; nf++) bfr[nf] = *(const bf16x8*)(smem + boff[nf][sub]);
            #pragma unroll
            for (int mf = 0; mf < 4; mf++)
                #pragma unroll
                for (int nf = 0; nf < NF; nf++)
                    acc[mf][nf] = __builtin_amdgcn_mfma_f32_16x16x32_bf16(af[mf], bfr[nf], acc[mf][nf], 0, 0, 0);
        }
        __syncthreads();
    }

    // ---- epilogue (C layout: col = lane&15, row = (lane>>4)*4 + i) ----
    const float* bia = bias + (size_t)e * NTOT;
    #pragma unroll
    for (int mf = 0; mf < 4; mf++) {
        #pragma unroll
        for (int i = 0; i < 4; i++) {
            int m = m0 + wm * 64 + mf * 16 + (lane >> 4) * 4 + i;
            if (m >= c) continue;
            size_t prow = (size_t)(seg + m);
            #pragma unroll
            for (int nf = 0; nf < NF; nf++) {
                int n = n0 + wn * NF * 16 + nf * 16 + (lane & 15);
                if (MODE == 0) {
                    float vv = acc[mf][nf][i] + bia[n];
                    vv = 0.5f * vv * (1.0f + erff(vv * 0.70710678118f));
                    ((bf16*)outp)[prow * NTOT + n] = __float2bfloat16(vv);
                } else {
                    ((float*)outp)[((size_t)ks * NPAIR + prow) * NTOT + n] = acc[mf][nf][i];
                }
            }
        }
    }
}

// ---------------- final combine: x[t] += sum_k w_k * (part0 + part1 + b2[e_k]) ----
__global__ __launch_bounds__(256) void combine(const float* __restrict__ op,
                                               const int* __restrict__ inv,
                                               const int* __restrict__ topi,
                                               const float* __restrict__ topw,
                                               const float* __restrict__ b2,
                                               float* __restrict__ x) {
    int idx = blockIdx.x * blockDim.x + threadIdx.x;
    if (idx >= T_TOK * H_DIM / 4) return;
    int t = idx / (H_DIM / 4);
    int cidx = idx % (H_DIM / 4);
    int p0 = inv[t * 2], p1 = inv[t * 2 + 1];
    int e0 = topi[t * 2], e1 = topi[t * 2 + 1];
    float w0 = topw[t * 2], w1 = topw[t * 2 + 1];
    float4 a0 = ((const float4*)(op + (size_t)p0 * H_DIM))[cidx];
    float4 a1 = ((const float4*)(op + ((size_t)NPAIR + p0) * H_DIM))[cidx];
    float4 c0 = ((const float4*)(op + (size_t)p1 * H_DIM))[cidx];
    float4 c1 = ((const float4*)(op + ((size_t)NPAIR + p1) * H_DIM))[cidx];
    float4 bi0 = ((const float4*)(b2 + (size_t)e0 * H_DIM))[cidx];
    float4 bi1 = ((const float4*)(b2 + (size_t)e1 * H_DIM))[cidx];
    float4* xp = (float4*)(x + (size_t)t * H_DIM) + cidx;
    float4 xo = *xp;
    xo.x += w0 * (a0.x + a1.x + bi0.x) + w1 * (c0.x + c1.x + bi1.x);
    xo.y += w0 * (a0.y + a1.y + bi0.y) + w1 * (c0.y + c1.y + bi1.y);
    xo.z += w0 * (a0.z + a1.z + bi0.z) + w1 * (c0.z + c1.z + bi1.z);
    xo.w += w0 * (a0.w + a1.w + bi0.w) + w1 * (c0.w + c1.w + bi1.w);
    *xp = xo;
}

extern "C" void kernel_launch(void* const* d_in, const int* in_sizes, int n_in,
                              void* d_out, int out_size, void* d_ws, size_t ws_size,
                              hipStream_t stream) {
    const int*   ids    = (const int*)d_in[0];
    const float* embed  = (const float*)d_in[1];
    const float* ln_g   = (const float*)d_in[2];
    const float* ln_b   = (const float*)d_in[3];
    const float* gate_w = (const float*)d_in[4];
    const float* gate_b = (const float*)d_in[5];
    const float* fc1_w  = (const float*)d_in[6];
    const float* fc1_b  = (const float*)d_in[7];
    const float* fc2_w  = (const float*)d_in[8];
    const float* fc2_b  = (const float*)d_in[9];

    float* x      = (float*)d_out;
    float* laux   = x + (size_t)T_TOK * H_DIM;
    float* counts = laux + 1;

    const size_t WELEM = (size_t)E_NUM * DF_DIM * H_DIM;   // per layer per matrix

    char* ws = (char*)d_ws;
    bf16* wb1   = (bf16*)ws;            ws += (size_t)2 * WELEM * sizeof(bf16);
    bf16* wb2   = (bf16*)ws;            ws += (size_t)2 * WELEM * sizeof(bf16);
    bf16* h1    = (bf16*)ws;            ws += (size_t)NPAIR * DF_DIM * sizeof(bf16);
    bf16* flatb = (bf16*)ws;            ws += (size_t)T_TOK * H_DIM * sizeof(bf16);
    float* op   = (float*)ws;           ws += (size_t)2 * NPAIR * H_DIM * sizeof(float);
    float* logits_tok = (float*)ws;     ws += (size_t)T_TOK * E_NUM * sizeof(float);
    int*  pair_tok = (int*)ws;          ws += NPAIR * sizeof(int);
    int*  inv      = (int*)ws;          ws += NPAIR * sizeof(int);
    int*  topi     = (int*)ws;          ws += T_TOK * K_TOP * sizeof(int);
    float* topw    = (float*)ws;        ws += T_TOK * K_TOP * sizeof(float);
    int*  cnt      = (int*)ws;          ws += E_NUM * sizeof(int);
    int*  offs     = (int*)ws;          ws += E_NUM * sizeof(int);

    hipMemsetAsync(laux, 0, 9 * sizeof(float), stream);

    conv_all<<<8192, 256, 0, stream>>>(fc1_w, fc2_w, wb1, wb2, (int)(2 * WELEM / 8));

    for (int l = 0; l < L_NUM; l++) {
        if (l == 0) {
            ln_gate<0><<<T_TOK, 256, 0, stream>>>(
                ids, embed, nullptr, nullptr, nullptr, nullptr, nullptr,
                x, ln_g, ln_b, gate_w, gate_b, flatb, logits_tok);
        } else {
            ln_gate<1><<<T_TOK, 256, 0, stream>>>(
                nullptr, nullptr, op, inv, topi, topw, fc2_b /* layer 0 bias */,
                x, ln_g + l * H_DIM, ln_b + l * H_DIM,
                gate_w + (size_t)l * E_NUM * H_DIM, gate_b + l * E_NUM,
                flatb, logits_tok);
        }
        route<<<1, 1024, 0, stream>>>(logits_tok, topi, topw, cnt, offs,
                                      pair_tok, inv, laux, counts);

        dim3 g1(DF_DIM / 128, E_NUM, 32);
        moe_gemm<4, 0, H_DIM, DF_DIM, 1><<<g1, 256, 0, stream>>>(
            flatb, wb1 + (size_t)l * WELEM,
            fc1_b + (size_t)l * E_NUM * DF_DIM, cnt, offs, pair_tok, (void*)h1);

        dim3 g2(2 * H_DIM / 64, E_NUM, 32);
        moe_gemm<2, 1, DF_DIM, H_DIM, 2><<<g2, 256, 0, stream>>>(
            h1, wb2 + (size_t)l * WELEM,
            fc2_b + (size_t)l * E_NUM * H_DIM, cnt, offs, pair_tok, (void*)op);
    }

    combine<<<(T_TOK * H_DIM / 4 + 255) / 256, 256, 0, stream>>>(
        op, inv, topi, topw, fc2_b + (size_t)(L_NUM - 1) * E_NUM * H_DIM, x);
}

// Round 21
// 330.975 us; speedup vs baseline: 1.0715x; 1.0715x over previous
//
#include <hip/hip_runtime.h>
#include <hip/hip_bf16.h>
#include <math.h>

#define T_TOK 2048
#define H_DIM 768
#define E_NUM 8
#define K_TOP 2
#define DF_DIM 3072
#define L_NUM 2
#define LN_EPS 1e-5f
#define NPAIR (T_TOK * K_TOP)

typedef __hip_bfloat16 bf16;
typedef __attribute__((ext_vector_type(8))) short bf16x8;   // 8 bf16 = 4 VGPRs
typedef __attribute__((ext_vector_type(4))) float f32x4;

// ---------------- LN + gate logits, with fused input production ----------------
// FUSE=0 (layer 0): input row = embed[ids[t]]; writes it to x (residual stream).
// FUSE=1 (layer 1): input row = x[t] + sum_k w_k*(op0[p_k]+op1[p_k]+b2[e_k]).
template<int FUSE>
__global__ __launch_bounds__(256) void ln_gate(
    const int* __restrict__ ids, const float* __restrict__ embed,
    const float* __restrict__ op, const int* __restrict__ inv,
    const int* __restrict__ topi, const float* __restrict__ topw,
    const float* __restrict__ b2,
    float* __restrict__ x, const float* __restrict__ g, const float* __restrict__ b,
    const float* __restrict__ gw, const float* __restrict__ gb,
    bf16* __restrict__ flat, float* __restrict__ logits_tok)
{
    int t = blockIdx.x;
    int tid = threadIdx.x;
    __shared__ float s[H_DIM];
    __shared__ float red[8];

    float v0, v1, v2;
    if (FUSE == 0) {
        const float* src = embed + (size_t)ids[t] * H_DIM;
        v0 = src[tid]; v1 = src[tid + 256]; v2 = src[tid + 512];
    } else {
        const float* xr = x + (size_t)t * H_DIM;
        int p0 = inv[t * 2], p1 = inv[t * 2 + 1];
        int e0 = topi[t * 2], e1 = topi[t * 2 + 1];
        float w0 = topw[t * 2], w1 = topw[t * 2 + 1];
        const float* o00 = op + (size_t)p0 * H_DIM;
        const float* o01 = op + ((size_t)NPAIR + p0) * H_DIM;
        const float* o10 = op + (size_t)p1 * H_DIM;
        const float* o11 = op + ((size_t)NPAIR + p1) * H_DIM;
        const float* bb0 = b2 + (size_t)e0 * H_DIM;
        const float* bb1 = b2 + (size_t)e1 * H_DIM;
        #pragma unroll
        for (int q = 0; q < 3; q++) {
            int o = tid + q * 256;
            float a0 = o00[o] + o01[o] + bb0[o];
            float a1 = o10[o] + o11[o] + bb1[o];
            float vv = xr[o] + w0 * a0 + w1 * a1;
            if (q == 0) v0 = vv; else if (q == 1) v1 = vv; else v2 = vv;
        }
    }
    float* xw = x + (size_t)t * H_DIM;
    xw[tid] = v0; xw[tid + 256] = v1; xw[tid + 512] = v2;

    float sum = v0 + v1 + v2;
    #pragma unroll
    for (int o = 32; o > 0; o >>= 1) sum += __shfl_down(sum, o);
    int wave = tid >> 6, lane = tid & 63;
    if (lane == 0) red[wave] = sum;
    __syncthreads();
    if (tid == 0) red[4] = (red[0] + red[1] + red[2] + red[3]) * (1.0f / H_DIM);
    __syncthreads();
    float mean = red[4];

    float d0 = v0 - mean, d1 = v1 - mean, d2 = v2 - mean;
    float ss = d0 * d0 + d1 * d1 + d2 * d2;
    #pragma unroll
    for (int o = 32; o > 0; o >>= 1) ss += __shfl_down(ss, o);
    if (lane == 0) red[wave] = ss;
    __syncthreads();
    if (tid == 0) red[4] = rsqrtf((red[0] + red[1] + red[2] + red[3]) * (1.0f / H_DIM) + LN_EPS);
    __syncthreads();
    float inv_s = red[4];

    float n0 = d0 * inv_s * g[tid]       + b[tid];
    float n1 = d1 * inv_s * g[tid + 256] + b[tid + 256];
    float n2 = d2 * inv_s * g[tid + 512] + b[tid + 512];
    s[tid] = n0; s[tid + 256] = n1; s[tid + 512] = n2;
    bf16* fr = flat + (size_t)t * H_DIM;
    fr[tid] = __float2bfloat16(n0);
    fr[tid + 256] = __float2bfloat16(n1);
    fr[tid + 512] = __float2bfloat16(n2);
    __syncthreads();

    #pragma unroll
    for (int ei = 0; ei < 2; ++ei) {
        int e = wave * 2 + ei;
        float p = 0.0f;
        const float* wrow = gw + (size_t)e * H_DIM;
        for (int j = lane; j < H_DIM; j += 64) p += s[j] * wrow[j];
        #pragma unroll
        for (int o = 32; o > 0; o >>= 1) p += __shfl_down(p, o);
        if (lane == 0) logits_tok[(size_t)t * E_NUM + e] = p + gb[e];
    }
}

// ---------------- routing: top2 + softmax + reduce + offsets + compaction ----------------
__global__ __launch_bounds__(1024) void route(
    const float* __restrict__ logits_tok,
    int* __restrict__ topi, float* __restrict__ topw,
    int* __restrict__ cnt, int* __restrict__ offs,
    int* __restrict__ pair_tok, int* __restrict__ inv,
    float* __restrict__ laux, float* __restrict__ counts_out)
{
    int tid = threadIdx.x;
    float pprob[E_NUM] = {0,0,0,0,0,0,0,0};
    int pcnt[E_NUM] = {0,0,0,0,0,0,0,0};
    int te[2][2];

    #pragma unroll
    for (int it = 0; it < 2; it++) {
        int t = tid + it * 1024;
        const float4* lp = (const float4*)(logits_tok + (size_t)t * E_NUM);
        float4 l0 = lp[0], l1 = lp[1];
        float lg[E_NUM] = {l0.x, l0.y, l0.z, l0.w, l1.x, l1.y, l1.z, l1.w};
        int i0 = 0; float m0 = lg[0];
        #pragma unroll
        for (int e = 1; e < E_NUM; e++) if (lg[e] > m0) { m0 = lg[e]; i0 = e; }
        int i1 = -1; float m1 = -1e30f;
        #pragma unroll
        for (int e = 0; e < E_NUM; e++) if (e != i0 && lg[e] > m1) { m1 = lg[e]; i1 = e; }
        float e1 = expf(m1 - m0);
        float is = 1.0f / (1.0f + e1);
        topi[t * 2] = i0; topi[t * 2 + 1] = i1;
        topw[t * 2] = is; topw[t * 2 + 1] = e1 * is;
        te[it][0] = i0; te[it][1] = i1;
        pcnt[i0]++; pcnt[i1]++;
        float sm = 0.0f, pe[E_NUM];
        #pragma unroll
        for (int e = 0; e < E_NUM; e++) { pe[e] = expf(lg[e] - m0); sm += pe[e]; }
        float isv = 1.0f / sm;
        #pragma unroll
        for (int e = 0; e < E_NUM; e++) pprob[e] += pe[e] * isv;
    }

    #pragma unroll
    for (int o = 32; o > 0; o >>= 1) {
        #pragma unroll
        for (int e = 0; e < E_NUM; e++) {
            pprob[e] += __shfl_down(pprob[e], o);
            pcnt[e]  += __shfl_down(pcnt[e], o);
        }
    }
    __shared__ float wprob[16][E_NUM];
    __shared__ int   wcnt[16][E_NUM];
    __shared__ int   soffs[E_NUM];
    __shared__ int   lfill[E_NUM];
    int wv = tid >> 6, lane = tid & 63;
    if (lane == 0) {
        #pragma unroll
        for (int e = 0; e < E_NUM; e++) { wprob[wv][e] = pprob[e]; wcnt[wv][e] = pcnt[e]; }
    }
    if (tid < E_NUM) lfill[tid] = 0;
    __syncthreads();
    if (tid == 0) {
        float ps[E_NUM]; int cs[E_NUM];
        #pragma unroll
        for (int e = 0; e < E_NUM; e++) {
            float p = 0.0f; int c = 0;
            for (int w = 0; w < 16; w++) { p += wprob[w][e]; c += wcnt[w][e]; }
            ps[e] = p; cs[e] = c;
        }
        int run = 0;
        #pragma unroll
        for (int e = 0; e < E_NUM; e++) { offs[e] = run; soffs[e] = run; cnt[e] = cs[e]; run += cs[e]; }
        float la = 0.0f;
        #pragma unroll
        for (int e = 0; e < E_NUM; e++) { float p = ps[e] * (1.0f / T_TOK); la += p * p; }
        laux[0] += la * E_NUM;
        #pragma unroll
        for (int e = 0; e < E_NUM; e++) counts_out[e] += (float)cs[e];
    }
    __syncthreads();

    #pragma unroll
    for (int it = 0; it < 2; it++) {
        int t = tid + it * 1024;
        #pragma unroll
        for (int k = 0; k < K_TOP; k++) {
            int e = te[it][k];
            int pos = atomicAdd(&lfill[e], 1);
            int p = soffs[e] + pos;
            pair_tok[p] = t;
            inv[t * 2 + k] = p;
        }
    }
}

// ---------------- MFMA grouped GEMM (R15 grid; f32 weights, in-register cvt) --------
// grid: (X, E, 32) m-slot slowest (contiguous-active-id spread over all CUs).
// KS=1: x = n-tile. KS=2: x = (n<<1)|ks. Blocks with m0 >= c exit immediately.
// Single-buffer LDS, 2-barrier K-loop, reg-staged loads; B rows read f32 and
// converted to bf16 in-register during the LDS write (no conv kernel needed —
// weights are fetched from HBM exactly once, as f32).
// MODE 0 (fc1): A = flat[pair_tok[row]], out = h1 bf16 with bias+GELU.
// MODE 1 (fc2): A = h1[seg+row], out = op[ks] f32 partial, NO bias.
template<int NF, int MODE, int KDIM, int NTOT, int KS>
__global__ __launch_bounds__(256) void moe_gemm(
    const bf16* __restrict__ Abase, const float* __restrict__ Wf,
    const float* __restrict__ bias,
    const int* __restrict__ cnt, const int* __restrict__ offs,
    const int* __restrict__ pair_tok, void* __restrict__ outp)
{
    constexpr int BM = 128;
    constexpr int BN = 32 * NF;
    constexpr int NISS = (BM + BN) / 16;   // 1KB staging issues per K-step
    constexpr int IPW  = NISS / 4;         // issues per thread
    constexpr int KD   = KDIM / KS;        // K range per block

    int e = blockIdx.y;
    int c = cnt[e];
    int m0 = blockIdx.z * BM;
    if (m0 >= c) return;
    int n0, ks;
    if (KS == 1) { n0 = blockIdx.x * BN; ks = 0; }
    else         { n0 = (blockIdx.x >> 1) * BN; ks = blockIdx.x & 1; }
    int kfirst = ks * KD;
    int seg = offs[e];
    const float* W = Wf + (size_t)e * NTOT * KDIM;

    __shared__ char smem[(BM + BN) * 64];  // A tile + B tile, bf16, swizzled

    int tid = threadIdx.x;
    int lane = tid & 63, wv = tid >> 6;
    int rloc = lane >> 2;                  // 16 rows per issue
    int kb = lane & 3;                     // 4 chunks of 8 elems per row

    // ---- per-lane staging setup (fixed across K loop) ----
    const bf16*  gA[IPW];
    const float* gW[IPW];
    bool isA[IPW];
    int ldsoff[IPW];
    #pragma unroll
    for (int q = 0; q < IPW; q++) {
        int j = wv + q * 4;                // issue id 0..NISS-1
        int row, base;
        gA[q] = nullptr; gW[q] = nullptr;
        if (j < 8) {                       // A rows (bf16)
            row = j * 16 + rloc;
            int m = m0 + row;
            int mm = (m < c) ? m : (c - 1);
            if (MODE == 0)
                gA[q] = Abase + (size_t)pair_tok[seg + mm] * KDIM + kb * 8;
            else
                gA[q] = Abase + (size_t)(seg + mm) * KDIM + kb * 8;
            base = 0;
            isA[q] = true;
        } else {                           // B rows (f32 weights)
            row = (j - 8) * 16 + rloc;
            gW[q] = W + (size_t)(n0 + row) * KDIM + kb * 8;
            base = BM * 64;
            isA[q] = false;
        }
        int line = row >> 1;
        int cc = ((row & 1) << 2) | kb;
        ldsoff[q] = base + line * 128 + ((cc ^ (line & 7)) << 4);
    }

    // ---- per-lane fragment read offsets ----
    int wm = wv >> 1, wn = wv & 1;
    int aoff[4], boff[NF];
    {
        int kbf = lane >> 4;
        #pragma unroll
        for (int mf = 0; mf < 4; mf++) {
            int row = wm * 64 + mf * 16 + (lane & 15);
            int line = row >> 1;
            int cc = ((row & 1) << 2) | kbf;
            aoff[mf] = line * 128 + ((cc ^ (line & 7)) << 4);
        }
        #pragma unroll
        for (int nf = 0; nf < NF; nf++) {
            int row = wn * NF * 16 + nf * 16 + (lane & 15);
            int line = row >> 1;
            int cc = ((row & 1) << 2) | kbf;
            boff[nf] = BM * 64 + line * 128 + ((cc ^ (line & 7)) << 4);
        }
    }

    f32x4 acc[4][NF];
    #pragma unroll
    for (int i = 0; i < 4; i++)
        #pragma unroll
        for (int j = 0; j < NF; j++) acc[i][j] = (f32x4){0.f, 0.f, 0.f, 0.f};

    // ---- K loop (2-barrier, single buffer) ----
    for (int k0 = kfirst; k0 < kfirst + KD; k0 += 32) {
        uint4 v[IPW];
        #pragma unroll
        for (int q = 0; q < IPW; q++) {
            if (isA[q]) {
                v[q] = *(const uint4*)(gA[q] + k0);
            } else {
                const float4* p = (const float4*)(gW[q] + k0);
                float4 a = p[0], bb = p[1];
                union { bf16 h[8]; uint4 u; } pk;
                pk.h[0] = __float2bfloat16(a.x);  pk.h[1] = __float2bfloat16(a.y);
                pk.h[2] = __float2bfloat16(a.z);  pk.h[3] = __float2bfloat16(a.w);
                pk.h[4] = __float2bfloat16(bb.x); pk.h[5] = __float2bfloat16(bb.y);
                pk.h[6] = __float2bfloat16(bb.z); pk.h[7] = __float2bfloat16(bb.w);
                v[q] = pk.u;
            }
        }
        #pragma unroll
        for (int q = 0; q < IPW; q++) *(uint4*)(smem + ldsoff[q]) = v[q];
        __syncthreads();
        bf16x8 af[4], bfr[NF];
        #pragma unroll
        for (int mf = 0; mf < 4; mf++) af[mf] = *(const bf16x8*)(smem + aoff[mf]);
        #pragma unroll
        for (int nf = 0; nf < NF; nf++) bfr[nf] = *(const bf16x8*)(smem + boff[nf]);
        #pragma unroll
        for (int mf = 0; mf < 4; mf++)
            #pragma unroll
            for (int nf = 0; nf < NF; nf++)
                acc[mf][nf] = __builtin_amdgcn_mfma_f32_16x16x32_bf16(af[mf], bfr[nf], acc[mf][nf], 0, 0, 0);
        __syncthreads();
    }

    // ---- epilogue (C layout: col = lane&15, row = (lane>>4)*4 + i) ----
    const float* bia = bias + (size_t)e * NTOT;
    #pragma unroll
    for (int mf = 0; mf < 4; mf++) {
        #pragma unroll
        for (int i = 0; i < 4; i++) {
            int m = m0 + wm * 64 + mf * 16 + (lane >> 4) * 4 + i;
            if (m >= c) continue;
            size_t prow = (size_t)(seg + m);
            #pragma unroll
            for (int nf = 0; nf < NF; nf++) {
                int n = n0 + wn * NF * 16 + nf * 16 + (lane & 15);
                if (MODE == 0) {
                    float vv = acc[mf][nf][i] + bia[n];
                    vv = 0.5f * vv * (1.0f + erff(vv * 0.70710678118f));
                    ((bf16*)outp)[prow * NTOT + n] = __float2bfloat16(vv);
                } else {
                    ((float*)outp)[((size_t)ks * NPAIR + prow) * NTOT + n] = acc[mf][nf][i];
                }
            }
        }
    }
}

// ---------------- final combine: x[t] += sum_k w_k * (part0 + part1 + b2[e_k]) ----
__global__ __launch_bounds__(256) void combine(const float* __restrict__ op,
                                               const int* __restrict__ inv,
                                               const int* __restrict__ topi,
                                               const float* __restrict__ topw,
                                               const float* __restrict__ b2,
                                               float* __restrict__ x) {
    int idx = blockIdx.x * blockDim.x + threadIdx.x;
    if (idx >= T_TOK * H_DIM / 4) return;
    int t = idx / (H_DIM / 4);
    int cidx = idx % (H_DIM / 4);
    int p0 = inv[t * 2], p1 = inv[t * 2 + 1];
    int e0 = topi[t * 2], e1 = topi[t * 2 + 1];
    float w0 = topw[t * 2], w1 = topw[t * 2 + 1];
    float4 a0 = ((const float4*)(op + (size_t)p0 * H_DIM))[cidx];
    float4 a1 = ((const float4*)(op + ((size_t)NPAIR + p0) * H_DIM))[cidx];
    float4 c0 = ((const float4*)(op + (size_t)p1 * H_DIM))[cidx];
    float4 c1 = ((const float4*)(op + ((size_t)NPAIR + p1) * H_DIM))[cidx];
    float4 bi0 = ((const float4*)(b2 + (size_t)e0 * H_DIM))[cidx];
    float4 bi1 = ((const float4*)(b2 + (size_t)e1 * H_DIM))[cidx];
    float4* xp = (float4*)(x + (size_t)t * H_DIM) + cidx;
    float4 xo = *xp;
    xo.x += w0 * (a0.x + a1.x + bi0.x) + w1 * (c0.x + c1.x + bi1.x);
    xo.y += w0 * (a0.y + a1.y + bi0.y) + w1 * (c0.y + c1.y + bi1.y);
    xo.z += w0 * (a0.z + a1.z + bi0.z) + w1 * (c0.z + c1.z + bi1.z);
    xo.w += w0 * (a0.w + a1.w + bi0.w) + w1 * (c0.w + c1.w + bi1.w);
    *xp = xo;
}

extern "C" void kernel_launch(void* const* d_in, const int* in_sizes, int n_in,
                              void* d_out, int out_size, void* d_ws, size_t ws_size,
                              hipStream_t stream) {
    const int*   ids    = (const int*)d_in[0];
    const float* embed  = (const float*)d_in[1];
    const float* ln_g   = (const float*)d_in[2];
    const float* ln_b   = (const float*)d_in[3];
    const float* gate_w = (const float*)d_in[4];
    const float* gate_b = (const float*)d_in[5];
    const float* fc1_w  = (const float*)d_in[6];
    const float* fc1_b  = (const float*)d_in[7];
    const float* fc2_w  = (const float*)d_in[8];
    const float* fc2_b  = (const float*)d_in[9];

    float* x      = (float*)d_out;
    float* laux   = x + (size_t)T_TOK * H_DIM;
    float* counts = laux + 1;

    const size_t WELEM = (size_t)E_NUM * DF_DIM * H_DIM;

    char* ws = (char*)d_ws;
    bf16* h1    = (bf16*)ws;            ws += (size_t)NPAIR * DF_DIM * sizeof(bf16);
    bf16* flatb = (bf16*)ws;            ws += (size_t)T_TOK * H_DIM * sizeof(bf16);
    float* op   = (float*)ws;           ws += (size_t)2 * NPAIR * H_DIM * sizeof(float);
    float* logits_tok = (float*)ws;     ws += (size_t)T_TOK * E_NUM * sizeof(float);
    int*  pair_tok = (int*)ws;          ws += NPAIR * sizeof(int);
    int*  inv      = (int*)ws;          ws += NPAIR * sizeof(int);
    int*  topi     = (int*)ws;          ws += T_TOK * K_TOP * sizeof(int);
    float* topw    = (float*)ws;        ws += T_TOK * K_TOP * sizeof(float);
    int*  cnt      = (int*)ws;          ws += E_NUM * sizeof(int);
    int*  offs     = (int*)ws;          ws += E_NUM * sizeof(int);

    hipMemsetAsync(laux, 0, 9 * sizeof(float), stream);

    for (int l = 0; l < L_NUM; l++) {
        if (l == 0) {
            ln_gate<0><<<T_TOK, 256, 0, stream>>>(
                ids, embed, nullptr, nullptr, nullptr, nullptr, nullptr,
                x, ln_g, ln_b, gate_w, gate_b, flatb, logits_tok);
        } else {
            ln_gate<1><<<T_TOK, 256, 0, stream>>>(
                nullptr, nullptr, op, inv, topi, topw, fc2_b /* layer 0 bias */,
                x, ln_g + l * H_DIM, ln_b + l * H_DIM,
                gate_w + (size_t)l * E_NUM * H_DIM, gate_b + l * E_NUM,
                flatb, logits_tok);
        }
        route<<<1, 1024, 0, stream>>>(logits_tok, topi, topw, cnt, offs,
                                      pair_tok, inv, laux, counts);

        // fc1: grid (24 n, 8 e, 32 m), f32 weights read directly (in-register cvt)
        dim3 g1(DF_DIM / 128, E_NUM, 32);
        moe_gemm<4, 0, H_DIM, DF_DIM, 1><<<g1, 256, 0, stream>>>(
            flatb, fc1_w + (size_t)l * WELEM,
            fc1_b + (size_t)l * E_NUM * DF_DIM, cnt, offs, pair_tok, (void*)h1);

        // fc2: grid (24 = n*ks, 8 e, 32 m), split-K=2, f32 weights read directly
        dim3 g2(2 * H_DIM / 64, E_NUM, 32);
        moe_gemm<2, 1, DF_DIM, H_DIM, 2><<<g2, 256, 0, stream>>>(
            h1, fc2_w + (size_t)l * WELEM,
            fc2_b + (size_t)l * E_NUM * H_DIM, cnt, offs, pair_tok, (void*)op);
    }

    combine<<<(T_TOK * H_DIM / 4 + 255) / 256, 256, 0, stream>>>(
        op, inv, topi, topw, fc2_b + (size_t)(L_NUM - 1) * E_NUM * H_DIM, x);
}